// Round 5
// baseline (1189.283 us; speedup 1.0000x reference)
//
#include <hip/hip_runtime.h>
#include <hip/hip_bf16.h>
#include <type_traits>

// Problem: PredicateLevelEncoder  B=32 T=64 N=36 VD=2048 H=512 S=300 Hc=256
// Device tensors are f32; MFMA operands converted to bf16 in ws; f32 outputs.

typedef __hip_bfloat16 bf16;
typedef unsigned int uint32;
typedef __attribute__((ext_vector_type(8))) short s8v;     // 8 bf16
typedef __attribute__((ext_vector_type(4))) float f4v;     // mfma accum
typedef __attribute__((ext_vector_type(4))) uint32 u32x4;  // raw tagged loads

__device__ inline f4v mfma16(s8v a, s8v b, f4v c) {
    return __builtin_amdgcn_mfma_f32_16x16x32_bf16(a, b, c, 0, 0, 0);
}
__device__ inline float sigf(float x) {
    return __builtin_amdgcn_rcpf(1.f + __expf(-x));
}
__device__ inline float tanh_(float x) {
    return 1.f - 2.f * __builtin_amdgcn_rcpf(1.f + __expf(2.f * x));
}
__device__ inline uint32 pack2(uint32 d0, uint32 d1) {
    // result = d0.low16 | d1.low16 << 16
#if __has_builtin(__builtin_amdgcn_perm)
    return __builtin_amdgcn_perm(d1, d0, 0x05040100u);
#else
    return (d0 & 0xffffu) | (d1 << 16);
#endif
}
__device__ inline void gload_lds16(const bf16* g, bf16* l) {
    __builtin_amdgcn_global_load_lds(
        (const __attribute__((address_space(1))) void*)g,
        (__attribute__((address_space(3))) void*)l, 16, 0, 0);
}

// ---------------------------------------------------------------------------
// Fused f32 -> bf16 conversion, 9 jobs in one launch (1024 elems per block).
// ---------------------------------------------------------------------------
struct CvtJobs {
    const float* src[9];
    bf16*        dst[9];
    int          start[10];
};

__global__ __launch_bounds__(256) void cvt_kernel(CvtJobs jobs) {
    int blk = blockIdx.x;
    int j = 0;
#pragma unroll
    for (int i = 1; i < 9; ++i) if (blk >= jobs.start[i]) j = i;
    int off = (blk - jobs.start[j]) * 1024 + threadIdx.x * 4;
    float4 v = *(const float4*)(jobs.src[j] + off);
    union { bf16 h[4]; uint2 u; } p;
    p.h[0] = __float2bfloat16(v.x);
    p.h[1] = __float2bfloat16(v.y);
    p.h[2] = __float2bfloat16(v.z);
    p.h[3] = __float2bfloat16(v.w);
    *(uint2*)(jobs.dst[j] + off) = p.u;
}

// ---------------------------------------------------------------------------
// LDS-staged GEMM (m97 structure): C[M,N] = A[M,K] * W[N,K]^T + b1 + b2.
// 128x128 tile, BK=64, 4 waves (2x2), each wave 64x64 = 4x4 16x16x32 frags.
// Staging via global_load_lds width-16 with XOR chunk swizzle (c ^= row&7):
// inverse swizzle applied to the GLOBAL source, forward on the LDS read (T21).
// permuteTB: output row r=b*64+t stored at row t*32+b (gates layout).
// ---------------------------------------------------------------------------
template <typename CT>
__global__ __launch_bounds__(256) void gemm_tile(
    const bf16* __restrict__ A, int lda,
    const bf16* __restrict__ W,
    const float* __restrict__ b1, const float* __restrict__ b2,
    CT* __restrict__ C, int ldc,
    int K, int tiles_n, int permuteTB)
{
    __shared__ bf16 As[128 * 64];
    __shared__ bf16 Bs[128 * 64];

    int tid = threadIdx.x;
    int w = tid >> 6, lane = tid & 63;
    int lo = lane & 15, hi = lane >> 4;
    int mt = blockIdx.x / tiles_n, nt = blockIdx.x % tiles_n;
    int wm = w >> 1, wn = w & 1;

    const bf16* Ab = A + (size_t)(mt * 128) * lda;
    const bf16* Wb = W + (size_t)(nt * 128) * K;

    f4v acc[4][4];
#pragma unroll
    for (int m = 0; m < 4; ++m)
#pragma unroll
        for (int n = 0; n < 4; ++n) acc[m][n] = (f4v){0.f, 0.f, 0.f, 0.f};

    int wbase = tid & 192;   // w * 64

    for (int k0 = 0; k0 < K; k0 += 64) {
        // stage A and B tiles (4 + 4 width-16 direct-to-LDS loads per thread)
#pragma unroll
        for (int i = 0; i < 4; ++i) {
            int ci = i * 256 + tid;
            int row = ci >> 3, c = ci & 7;
            int gc = c ^ (row & 7);
            gload_lds16(Ab + (size_t)row * lda + k0 + gc * 8,
                        As + (i * 256 + wbase) * 8);
            gload_lds16(Wb + (size_t)row * K + k0 + gc * 8,
                        Bs + (i * 256 + wbase) * 8);
        }
        __syncthreads();

#pragma unroll
        for (int kt = 0; kt < 2; ++kt) {
            s8v a[4], b[4];
            int sw = ((kt * 4 + hi) ^ (lo & 7)) * 8;
#pragma unroll
            for (int m = 0; m < 4; ++m)
                a[m] = *(const s8v*)(As + (wm * 64 + m * 16 + lo) * 64 + sw);
#pragma unroll
            for (int n = 0; n < 4; ++n)
                b[n] = *(const s8v*)(Bs + (wn * 64 + n * 16 + lo) * 64 + sw);
#pragma unroll
            for (int m = 0; m < 4; ++m)
#pragma unroll
                for (int n = 0; n < 4; ++n)
                    acc[m][n] = mfma16(a[m], b[n], acc[m][n]);
        }
        __syncthreads();
    }

#pragma unroll
    for (int n = 0; n < 4; ++n) {
        int cc = nt * 128 + wn * 64 + n * 16 + lo;
        float bv = (b1 ? b1[cc] : 0.f) + (b2 ? b2[cc] : 0.f);
#pragma unroll
        for (int m = 0; m < 4; ++m) {
            int rbase = mt * 128 + wm * 64 + m * 16 + hi * 4;
#pragma unroll
            for (int i = 0; i < 4; ++i) {
                int r = rbase + i;
                int rr = permuteTB ? ((r & 63) * 32 + (r >> 6)) : r;
                float v = acc[m][n][i] + bv;
                if constexpr (std::is_same<CT, float>::value)
                    C[(size_t)rr * ldc + cc] = v;
                else
                    C[(size_t)rr * ldc + cc] = __float2bfloat16(v);
            }
        }
    }
}

// ---------------------------------------------------------------------------
// Fused additive attention (unchanged; softmax-factored weighted sum).
// ---------------------------------------------------------------------------
__global__ __launch_bounds__(256) void attn_kernel(
    const float* __restrict__ Wf,   // [2048][512]
    const float* __restrict__ Uo,   // [32][36][512]
    const float* __restrict__ wW,   // [512]
    const float* __restrict__ wB,   // [1]
    bf16* __restrict__ feats)       // [2048][1024]
{
    int bt = blockIdx.x, b = bt >> 6;
    int wv = threadIdx.x >> 6, lane = threadIdx.x & 63;
    __shared__ float s_aw[36];

    float wfr[8], wr[8];
    const float* wfrow = Wf + (size_t)bt * 512 + lane * 8;
#pragma unroll
    for (int i = 0; i < 8; ++i) {
        wfr[i] = wfrow[i];
        wr[i]  = wW[lane * 8 + i];
    }
    float wbv = wB[0];

    for (int n = wv; n < 36; n += 4) {
        const float* uo = Uo + ((size_t)b * 36 + n) * 512 + lane * 8;
        float s = 0.f;
#pragma unroll
        for (int i = 0; i < 8; ++i) s += wr[i] * tanh_(wfr[i] + uo[i]);
#pragma unroll
        for (int off = 32; off; off >>= 1) s += __shfl_xor(s, off);
        if (lane == 0) s_aw[n] = s + wbv;
    }
    __syncthreads();
    if (threadIdx.x == 0) {
        float mx = -1e30f;
#pragma unroll
        for (int n = 0; n < 36; ++n) mx = fmaxf(mx, s_aw[n]);
        float e[36], sum = 0.f;
#pragma unroll
        for (int n = 0; n < 36; ++n) { e[n] = __expf(s_aw[n] - mx); sum += e[n]; }
        float r = __builtin_amdgcn_rcpf(sum);
#pragma unroll
        for (int n = 0; n < 36; ++n) s_aw[n] = e[n] * r;
    }
    __syncthreads();

    int h0 = threadIdx.x * 2;
    const float* wf2 = Wf + (size_t)bt * 512 + h0;
    float a0 = wf2[0], a1 = wf2[1];
    for (int n = 0; n < 36; ++n) {
        float awn = s_aw[n];
        const float* uo = Uo + ((size_t)b * 36 + n) * 512 + h0;
        a0 += awn * uo[0];
        a1 += awn * uo[1];
    }
    feats[(size_t)bt * 1024 + 512 + h0]     = __float2bfloat16(a0);
    feats[(size_t)bt * 1024 + 512 + h0 + 1] = __float2bfloat16(a1);
}

// ---------------------------------------------------------------------------
// BiLSTM recurrent part. 8 blocks (4 j-slices x 2 dirs), Whh in registers.
//
// Tagged-h sync (R4 post-mortem): each h element is one dword
// (tag<<16 | bf16), stored relaxed/agent (fire-and-forget, no drain, no
// flags, no barrier). Readers poll by reloading the data itself (32
// pipelined dwordx4 sc1, one vmcnt(0)) and retry until all 128 tags == t.
// Per-dword tags are tear-proof; slot parity + lockstep makes overwrites
// race-free; 0xAA ws poison never matches a tag, so init self-syncs.
// ---------------------------------------------------------------------------
__global__ __launch_bounds__(256, 1) void lstm_kernel(
    const bf16* __restrict__ WhhF, const bf16* __restrict__ WhhB, // [1024][256]
    const float* __restrict__ gatesF, const float* __restrict__ gatesB, // [64][32][1024]
    uint32* __restrict__ hx,  // [2 dir][2 slot][32][256] tagged dwords
    float* __restrict__ out)  // [32][64][512]
{
    int bi  = blockIdx.x;
    int dir = bi >> 2;
    int jb  = (bi & 3) * 64;
    int wv = threadIdx.x >> 6, lane = threadIdx.x & 63;
    int lo = lane & 15, hi = lane >> 4;

    const bf16*  Whh   = dir ? WhhB : WhhF;
    const float* gates = dir ? gatesB : gatesF;
    uint32* hxd = hx + (size_t)dir * 16384;
    int j0 = jb + wv * 16;

    // Whh B-fragments, resident (32 s8v = 128 VGPR)
    s8v whhF[4][8];
#pragma unroll
    for (int g = 0; g < 4; ++g)
#pragma unroll
        for (int kt = 0; kt < 8; ++kt)
            whhF[g][kt] = *(const s8v*)(Whh + (size_t)(g * 256 + j0 + lo) * 256 + kt * 32 + hi * 8);

    // init: slot 0, own j-slice, tag 0, value 0  (dword == 0)
    for (int x = threadIdx.x; x < 2048; x += 256) {
        int b = x >> 6, j = jb + (x & 63);
        __hip_atomic_store(&hxd[b * 256 + j], 0u, __ATOMIC_RELAXED,
                           __HIP_MEMORY_SCOPE_AGENT);
    }

    float cst[2][4] = {{0.f,0.f,0.f,0.f},{0.f,0.f,0.f,0.f}};

    for (int t = 0; t < 64; ++t) {
        const uint32* hr = hxd + (t & 1) * 8192;
        uint32*       hw = hxd + ((t & 1) ^ 1) * 8192;
        int tp = dir ? (63 - t) : t;
        const float* gin = gates + (size_t)tp * 32 * 1024;

        // gate inputs (independent of h) -- issue before the poll
        float gv[2][4][4];
#pragma unroll
        for (int m = 0; m < 2; ++m)
#pragma unroll
            for (int i = 0; i < 4; ++i) {
                int b = m * 16 + hi * 4 + i;
#pragma unroll
                for (int g = 0; g < 4; ++g)
                    gv[m][g][i] = gin[(size_t)b * 1024 + g * 256 + j0 + lo];
            }

        // poll+load h(t): retry full tagged load until every tag == t
        u32x4 rw[32];
        uint32 tagw = (uint32)t << 16;
        const uint32* p0 = hr + lo * 256 + hi * 8;          // m=0 rows
        const uint32* p1 = p0 + 16 * 256;                   // m=1 rows
        for (;;) {
            asm volatile(
                "global_load_dwordx4 %0, %32, off sc1\n\t"
                "global_load_dwordx4 %1, %32, off offset:16 sc1\n\t"
                "global_load_dwordx4 %2, %32, off offset:128 sc1\n\t"
                "global_load_dwordx4 %3, %32, off offset:144 sc1\n\t"
                "global_load_dwordx4 %4, %32, off offset:256 sc1\n\t"
                "global_load_dwordx4 %5, %32, off offset:272 sc1\n\t"
                "global_load_dwordx4 %6, %32, off offset:384 sc1\n\t"
                "global_load_dwordx4 %7, %32, off offset:400 sc1\n\t"
                "global_load_dwordx4 %8, %32, off offset:512 sc1\n\t"
                "global_load_dwordx4 %9, %32, off offset:528 sc1\n\t"
                "global_load_dwordx4 %10, %32, off offset:640 sc1\n\t"
                "global_load_dwordx4 %11, %32, off offset:656 sc1\n\t"
                "global_load_dwordx4 %12, %32, off offset:768 sc1\n\t"
                "global_load_dwordx4 %13, %32, off offset:784 sc1\n\t"
                "global_load_dwordx4 %14, %32, off offset:896 sc1\n\t"
                "global_load_dwordx4 %15, %32, off offset:912 sc1\n\t"
                "global_load_dwordx4 %16, %33, off sc1\n\t"
                "global_load_dwordx4 %17, %33, off offset:16 sc1\n\t"
                "global_load_dwordx4 %18, %33, off offset:128 sc1\n\t"
                "global_load_dwordx4 %19, %33, off offset:144 sc1\n\t"
                "global_load_dwordx4 %20, %33, off offset:256 sc1\n\t"
                "global_load_dwordx4 %21, %33, off offset:272 sc1\n\t"
                "global_load_dwordx4 %22, %33, off offset:384 sc1\n\t"
                "global_load_dwordx4 %23, %33, off offset:400 sc1\n\t"
                "global_load_dwordx4 %24, %33, off offset:512 sc1\n\t"
                "global_load_dwordx4 %25, %33, off offset:528 sc1\n\t"
                "global_load_dwordx4 %26, %33, off offset:640 sc1\n\t"
                "global_load_dwordx4 %27, %33, off offset:656 sc1\n\t"
                "global_load_dwordx4 %28, %33, off offset:768 sc1\n\t"
                "global_load_dwordx4 %29, %33, off offset:784 sc1\n\t"
                "global_load_dwordx4 %30, %33, off offset:896 sc1\n\t"
                "global_load_dwordx4 %31, %33, off offset:912 sc1\n\t"
                "s_waitcnt vmcnt(0)"
                : "=v"(rw[0]), "=v"(rw[1]), "=v"(rw[2]), "=v"(rw[3]),
                  "=v"(rw[4]), "=v"(rw[5]), "=v"(rw[6]), "=v"(rw[7]),
                  "=v"(rw[8]), "=v"(rw[9]), "=v"(rw[10]), "=v"(rw[11]),
                  "=v"(rw[12]), "=v"(rw[13]), "=v"(rw[14]), "=v"(rw[15]),
                  "=v"(rw[16]), "=v"(rw[17]), "=v"(rw[18]), "=v"(rw[19]),
                  "=v"(rw[20]), "=v"(rw[21]), "=v"(rw[22]), "=v"(rw[23]),
                  "=v"(rw[24]), "=v"(rw[25]), "=v"(rw[26]), "=v"(rw[27]),
                  "=v"(rw[28]), "=v"(rw[29]), "=v"(rw[30]), "=v"(rw[31])
                : "v"(p0), "v"(p1)
                : "memory");
            uint32 bad = 0;
#pragma unroll
            for (int q = 0; q < 32; ++q) {
                bad |= rw[q][0] ^ tagw;
                bad |= rw[q][1] ^ tagw;
                bad |= rw[q][2] ^ tagw;
                bad |= rw[q][3] ^ tagw;
            }
            if (!__any(bad >> 16)) break;
        }

        // unpack + MFMA
        f4v acc[2][4];
#pragma unroll
        for (int m = 0; m < 2; ++m)
#pragma unroll
            for (int g = 0; g < 4; ++g) acc[m][g] = (f4v){0.f,0.f,0.f,0.f};
#pragma unroll
        for (int kt = 0; kt < 8; ++kt)
#pragma unroll
            for (int m = 0; m < 2; ++m) {
                u32x4 A0 = rw[m * 16 + kt * 2];
                u32x4 A1 = rw[m * 16 + kt * 2 + 1];
                union { uint32 u[4]; s8v v; } tt;
                tt.u[0] = pack2(A0[0], A0[1]);
                tt.u[1] = pack2(A0[2], A0[3]);
                tt.u[2] = pack2(A1[0], A1[1]);
                tt.u[3] = pack2(A1[2], A1[3]);
#pragma unroll
                for (int g = 0; g < 4; ++g)
                    acc[m][g] = mfma16(tt.v, whhF[g][kt], acc[m][g]);
            }

        float hv[2][4];
#pragma unroll
        for (int m = 0; m < 2; ++m)
#pragma unroll
            for (int i = 0; i < 4; ++i) {
                float xi = acc[m][0][i] + gv[m][0][i];
                float xf = acc[m][1][i] + gv[m][1][i];
                float xg = acc[m][2][i] + gv[m][2][i];
                float xo = acc[m][3][i] + gv[m][3][i];
                float c = sigf(xf) * cst[m][i] + sigf(xi) * tanh_(xg);
                cst[m][i] = c;
                hv[m][i] = sigf(xo) * tanh_(c);
            }

        // tagged h stores first (critical path), then output stores
        if (t < 63) {
            uint32 tw = (uint32)(t + 1) << 16;
#pragma unroll
            for (int m = 0; m < 2; ++m)
#pragma unroll
                for (int i = 0; i < 4; ++i) {
                    int b = m * 16 + hi * 4 + i;
                    uint32 d = tw | (uint32)__bfloat16_as_ushort(__float2bfloat16(hv[m][i]));
                    __hip_atomic_store(&hw[b * 256 + j0 + lo], d,
                                       __ATOMIC_RELAXED, __HIP_MEMORY_SCOPE_AGENT);
                }
        }
#pragma unroll
        for (int m = 0; m < 2; ++m)
#pragma unroll
            for (int i = 0; i < 4; ++i) {
                int b = m * 16 + hi * 4 + i;
                out[((size_t)b * 64 + tp) * 512 + dir * 256 + j0 + lo] = hv[m][i];
            }
    }
}

// ---------------------------------------------------------------------------
// action = max over T of output; action_semantics = action @ fc_W^T + fc_b
// ---------------------------------------------------------------------------
__global__ __launch_bounds__(256) void final_kernel(
    const float* __restrict__ out,   // [32][64][512]
    const float* __restrict__ fcW,   // [300][512]
    const float* __restrict__ fcb,   // [300]
    float* __restrict__ osem)        // [32][300]
{
    int b = blockIdx.x, tid = threadIdx.x;
    __shared__ float act[512];
    for (int h = tid; h < 512; h += 256) {
        float m = -1e30f;
        const float* p = out + (size_t)b * 64 * 512 + h;
#pragma unroll 8
        for (int t = 0; t < 64; ++t) m = fmaxf(m, p[t * 512]);
        act[h] = m;
    }
    __syncthreads();
    int wv = tid >> 6, lane = tid & 63;
    for (int s = wv; s < 300; s += 4) {
        const float* wrow = fcW + (size_t)s * 512 + lane * 8;
        float a = 0.f;
#pragma unroll
        for (int i = 0; i < 8; ++i) a += act[lane * 8 + i] * wrow[i];
#pragma unroll
        for (int off = 32; off; off >>= 1) a += __shfl_xor(a, off);
        if (lane == 0) osem[b * 300 + s] = a + fcb[s];
    }
}

// ---------------------------------------------------------------------------
extern "C" void kernel_launch(void* const* d_in, const int* in_sizes, int n_in,
                              void* d_out, int out_size, void* d_ws, size_t ws_size,
                              hipStream_t stream)
{
    const float* visual  = (const float*)d_in[0];
    const float* objects = (const float*)d_in[1];
    const float* lin_W   = (const float*)d_in[2];
    const float* lin_b   = (const float*)d_in[3];
    const float* W_W     = (const float*)d_in[4];
    const float* W_b     = (const float*)d_in[5];
    const float* U_W     = (const float*)d_in[6];
    const float* U_b     = (const float*)d_in[7];
    const float* b_attn  = (const float*)d_in[8];
    const float* w_W     = (const float*)d_in[9];
    const float* w_b     = (const float*)d_in[10];
    const float* Wih_f   = (const float*)d_in[11];
    const float* Whh_f   = (const float*)d_in[12];
    const float* bih_f   = (const float*)d_in[13];
    const float* bhh_f   = (const float*)d_in[14];
    const float* Wih_b   = (const float*)d_in[15];
    const float* Whh_b   = (const float*)d_in[16];
    const float* bih_b   = (const float*)d_in[17];
    const float* bhh_b   = (const float*)d_in[18];
    const float* fc_W    = (const float*)d_in[19];
    const float* fc_b    = (const float*)d_in[20];

    char* ws = (char*)d_ws;
    size_t o = 0;
    bf16*   feats   = (bf16*)(ws + o);   o += (size_t)2048 * 1024 * 2;
    float*  Wf      = (float*)(ws + o);  o += (size_t)2048 * 512 * 4;
    float*  Uo      = (float*)(ws + o);  o += (size_t)1152 * 512 * 4;
    float*  gatesF  = (float*)(ws + o);  o += (size_t)2048 * 1024 * 4;
    float*  gatesB  = (float*)(ws + o);  o += (size_t)2048 * 1024 * 4;
    uint32* hx      = (uint32*)(ws + o); o += (size_t)2 * 16384 * 4;
    bf16*  visual_b  = (bf16*)(ws + o); o += (size_t)4194304 * 2;
    bf16*  objects_b = (bf16*)(ws + o); o += (size_t)589824 * 2;
    bf16*  lin_Wb    = (bf16*)(ws + o); o += (size_t)1048576 * 2;
    bf16*  W_Wb      = (bf16*)(ws + o); o += (size_t)262144 * 2;
    bf16*  U_Wb      = (bf16*)(ws + o); o += (size_t)262144 * 2;
    bf16*  Wih_fb    = (bf16*)(ws + o); o += (size_t)1048576 * 2;
    bf16*  Whh_fb    = (bf16*)(ws + o); o += (size_t)262144 * 2;
    bf16*  Wih_bb    = (bf16*)(ws + o); o += (size_t)1048576 * 2;
    bf16*  Whh_bb    = (bf16*)(ws + o); o += (size_t)262144 * 2;

    CvtJobs cj;
    const float* srcs[9] = {visual, objects, lin_W, W_W, U_W, Wih_f, Whh_f, Wih_b, Whh_b};
    bf16* dsts[9] = {visual_b, objects_b, lin_Wb, W_Wb, U_Wb, Wih_fb, Whh_fb, Wih_bb, Whh_bb};
    int ns[9] = {4194304, 589824, 1048576, 262144, 262144, 1048576, 262144, 1048576, 262144};
    int acc_b = 0;
    for (int i = 0; i < 9; ++i) {
        cj.src[i] = srcs[i];
        cj.dst[i] = dsts[i];
        cj.start[i] = acc_b;
        acc_b += ns[i] / 1024;
    }
    cj.start[9] = acc_b;

    dim3 blk(256);
    cvt_kernel<<<acc_b, blk, 0, stream>>>(cj);

    // f3d -> feats[:, :512]   (M=2048,N=512,K=2048), 16x4 tiles
    gemm_tile<bf16><<<64, blk, 0, stream>>>(visual_b, 2048, lin_Wb, lin_b, nullptr,
                                            feats, 1024, 2048, 4, 0);
    // Uo' = objects@U_W^T + (U_b + b_attn)   (M=1152,N=512,K=512), 9x4 tiles
    gemm_tile<float><<<36, blk, 0, stream>>>(objects_b, 512, U_Wb, U_b, b_attn,
                                             Uo, 512, 512, 4, 0);
    // Wf = f3d@W_W^T + W_b   (M=2048,N=512,K=512), 16x4 tiles
    gemm_tile<float><<<64, blk, 0, stream>>>(feats, 1024, W_Wb, W_b, nullptr,
                                             Wf, 512, 512, 4, 0);
    // fused attention -> feats[:, 512:]
    attn_kernel<<<2048, blk, 0, stream>>>(Wf, Uo, w_W, w_b, feats);
    // gate input projections -> [T][B][1024]   (M=2048,N=1024,K=1024), 16x8
    gemm_tile<float><<<128, blk, 0, stream>>>(feats, 1024, Wih_fb, bih_f, bhh_f,
                                              gatesF, 1024, 1024, 8, 1);
    gemm_tile<float><<<128, blk, 0, stream>>>(feats, 1024, Wih_bb, bih_b, bhh_b,
                                              gatesB, 1024, 1024, 8, 1);
    // recurrent BiLSTM -> d_out[0 .. 1048575]
    lstm_kernel<<<8, blk, 0, stream>>>(Whh_fb, Whh_bb, gatesF, gatesB, hx,
                                       (float*)d_out);
    // action max + fc -> d_out[1048576 ..]
    final_kernel<<<32, blk, 0, stream>>>((float*)d_out, fc_W, fc_b,
                                         (float*)d_out + 1048576);
}

// Round 6
// 591.716 us; speedup vs baseline: 2.0099x; 2.0099x over previous
//
#include <hip/hip_runtime.h>
#include <hip/hip_bf16.h>
#include <type_traits>

// Problem: PredicateLevelEncoder  B=32 T=64 N=36 VD=2048 H=512 S=300 Hc=256
// Device tensors are f32; MFMA operands converted to bf16 in ws; f32 outputs.

typedef __hip_bfloat16 bf16;
typedef unsigned int uint32;
typedef __attribute__((ext_vector_type(8))) short s8v;     // 8 bf16
typedef __attribute__((ext_vector_type(4))) float f4v;     // mfma accum
typedef __attribute__((ext_vector_type(4))) int   i32x4;   // flag poll

__device__ inline f4v mfma16(s8v a, s8v b, f4v c) {
    return __builtin_amdgcn_mfma_f32_16x16x32_bf16(a, b, c, 0, 0, 0);
}
__device__ inline float sigf(float x) {
    return __builtin_amdgcn_rcpf(1.f + __expf(-x));
}
__device__ inline float tanh_(float x) {
    return 1.f - 2.f * __builtin_amdgcn_rcpf(1.f + __expf(2.f * x));
}
__device__ inline void gload_lds16(const bf16* g, bf16* l) {
    __builtin_amdgcn_global_load_lds(
        (const __attribute__((address_space(1))) void*)g,
        (__attribute__((address_space(3))) void*)l, 16, 0, 0);
}

// ---------------------------------------------------------------------------
// Fused f32 -> bf16 conversion, 9 jobs in one launch (1024 elems per block).
// ---------------------------------------------------------------------------
struct CvtJobs {
    const float* src[9];
    bf16*        dst[9];
    int          start[10];
};

__global__ __launch_bounds__(256) void cvt_kernel(CvtJobs jobs) {
    int blk = blockIdx.x;
    int j = 0;
#pragma unroll
    for (int i = 1; i < 9; ++i) if (blk >= jobs.start[i]) j = i;
    int off = (blk - jobs.start[j]) * 1024 + threadIdx.x * 4;
    float4 v = *(const float4*)(jobs.src[j] + off);
    union { bf16 h[4]; uint2 u; } p;
    p.h[0] = __float2bfloat16(v.x);
    p.h[1] = __float2bfloat16(v.y);
    p.h[2] = __float2bfloat16(v.z);
    p.h[3] = __float2bfloat16(v.w);
    *(uint2*)(jobs.dst[j] + off) = p.u;
}

// ---------------------------------------------------------------------------
// LDS-staged GEMM (m97 structure): C[M,N] = A[M,K] * W[N,K]^T + b1 + b2.
// 128x128 tile, BK=64, 4 waves (2x2), each wave 64x64 = 4x4 16x16x32 frags.
// ---------------------------------------------------------------------------
template <typename CT>
__global__ __launch_bounds__(256) void gemm_tile(
    const bf16* __restrict__ A, int lda,
    const bf16* __restrict__ W,
    const float* __restrict__ b1, const float* __restrict__ b2,
    CT* __restrict__ C, int ldc,
    int K, int tiles_n, int permuteTB)
{
    __shared__ bf16 As[128 * 64];
    __shared__ bf16 Bs[128 * 64];

    int tid = threadIdx.x;
    int w = tid >> 6, lane = tid & 63;
    int lo = lane & 15, hi = lane >> 4;
    int mt = blockIdx.x / tiles_n, nt = blockIdx.x % tiles_n;
    int wm = w >> 1, wn = w & 1;

    const bf16* Ab = A + (size_t)(mt * 128) * lda;
    const bf16* Wb = W + (size_t)(nt * 128) * K;

    f4v acc[4][4];
#pragma unroll
    for (int m = 0; m < 4; ++m)
#pragma unroll
        for (int n = 0; n < 4; ++n) acc[m][n] = (f4v){0.f, 0.f, 0.f, 0.f};

    int wbase = tid & 192;   // w * 64

    for (int k0 = 0; k0 < K; k0 += 64) {
#pragma unroll
        for (int i = 0; i < 4; ++i) {
            int ci = i * 256 + tid;
            int row = ci >> 3, c = ci & 7;
            int gc = c ^ (row & 7);
            gload_lds16(Ab + (size_t)row * lda + k0 + gc * 8,
                        As + (i * 256 + wbase) * 8);
            gload_lds16(Wb + (size_t)row * K + k0 + gc * 8,
                        Bs + (i * 256 + wbase) * 8);
        }
        __syncthreads();

#pragma unroll
        for (int kt = 0; kt < 2; ++kt) {
            s8v a[4], b[4];
            int sw = ((kt * 4 + hi) ^ (lo & 7)) * 8;
#pragma unroll
            for (int m = 0; m < 4; ++m)
                a[m] = *(const s8v*)(As + (wm * 64 + m * 16 + lo) * 64 + sw);
#pragma unroll
            for (int n = 0; n < 4; ++n)
                b[n] = *(const s8v*)(Bs + (wn * 64 + n * 16 + lo) * 64 + sw);
#pragma unroll
            for (int m = 0; m < 4; ++m)
#pragma unroll
                for (int n = 0; n < 4; ++n)
                    acc[m][n] = mfma16(a[m], b[n], acc[m][n]);
        }
        __syncthreads();
    }

#pragma unroll
    for (int n = 0; n < 4; ++n) {
        int cc = nt * 128 + wn * 64 + n * 16 + lo;
        float bv = (b1 ? b1[cc] : 0.f) + (b2 ? b2[cc] : 0.f);
#pragma unroll
        for (int m = 0; m < 4; ++m) {
            int rbase = mt * 128 + wm * 64 + m * 16 + hi * 4;
#pragma unroll
            for (int i = 0; i < 4; ++i) {
                int r = rbase + i;
                int rr = permuteTB ? ((r & 63) * 32 + (r >> 6)) : r;
                float v = acc[m][n][i] + bv;
                if constexpr (std::is_same<CT, float>::value)
                    C[(size_t)rr * ldc + cc] = v;
                else
                    C[(size_t)rr * ldc + cc] = __float2bfloat16(v);
            }
        }
    }
}

// ---------------------------------------------------------------------------
// Fused additive attention (unchanged).
// ---------------------------------------------------------------------------
__global__ __launch_bounds__(256) void attn_kernel(
    const float* __restrict__ Wf,   // [2048][512]
    const float* __restrict__ Uo,   // [32][36][512]
    const float* __restrict__ wW,   // [512]
    const float* __restrict__ wB,   // [1]
    bf16* __restrict__ feats)       // [2048][1024]
{
    int bt = blockIdx.x, b = bt >> 6;
    int wv = threadIdx.x >> 6, lane = threadIdx.x & 63;
    __shared__ float s_aw[36];

    float wfr[8], wr[8];
    const float* wfrow = Wf + (size_t)bt * 512 + lane * 8;
#pragma unroll
    for (int i = 0; i < 8; ++i) {
        wfr[i] = wfrow[i];
        wr[i]  = wW[lane * 8 + i];
    }
    float wbv = wB[0];

    for (int n = wv; n < 36; n += 4) {
        const float* uo = Uo + ((size_t)b * 36 + n) * 512 + lane * 8;
        float s = 0.f;
#pragma unroll
        for (int i = 0; i < 8; ++i) s += wr[i] * tanh_(wfr[i] + uo[i]);
#pragma unroll
        for (int off = 32; off; off >>= 1) s += __shfl_xor(s, off);
        if (lane == 0) s_aw[n] = s + wbv;
    }
    __syncthreads();
    if (threadIdx.x == 0) {
        float mx = -1e30f;
#pragma unroll
        for (int n = 0; n < 36; ++n) mx = fmaxf(mx, s_aw[n]);
        float e[36], sum = 0.f;
#pragma unroll
        for (int n = 0; n < 36; ++n) { e[n] = __expf(s_aw[n] - mx); sum += e[n]; }
        float r = __builtin_amdgcn_rcpf(sum);
#pragma unroll
        for (int n = 0; n < 36; ++n) s_aw[n] = e[n] * r;
    }
    __syncthreads();

    int h0 = threadIdx.x * 2;
    const float* wf2 = Wf + (size_t)bt * 512 + h0;
    float a0 = wf2[0], a1 = wf2[1];
    for (int n = 0; n < 36; ++n) {
        float awn = s_aw[n];
        const float* uo = Uo + ((size_t)b * 36 + n) * 512 + h0;
        a0 += awn * uo[0];
        a1 += awn * uo[1];
    }
    feats[(size_t)bt * 1024 + 512 + h0]     = __float2bfloat16(a0);
    feats[(size_t)bt * 1024 + 512 + h0 + 1] = __float2bfloat16(a1);
}

// ---------------------------------------------------------------------------
// BiLSTM recurrent part, batch-split + direction-merged (R5 post-mortem).
// 8 blocks = 2 batch-groups (16 batches) x 4 j-slices. Each block computes
// BOTH directions for its 16 batches / 64 cell-cols. One flag + one poll +
// one drain per iteration serves two direction-steps; fwd h-store latency
// hides under bwd compute. Flags: 4 consecutive dwords per group -> single
// wave-uniform dwordx4 sc1 poll. h exchange: R4's proven packed-dword
// protocol (relaxed agent stores; drain via __syncthreads before flag bump;
// read-before-overwrite guarded by the poll).
// VGPR: Whh both dirs 256 + aF 64 + misc ~= 410 -> launch_bounds(256,1).
// ---------------------------------------------------------------------------
__device__ inline void poll4(const int* p, int need) {
    for (;;) {
        i32x4 f;
        asm volatile("global_load_dwordx4 %0, %1, off sc1\n\t"
                     "s_waitcnt vmcnt(0)"
                     : "=v"(f) : "v"(p) : "memory");
        if (f[0] >= need && f[1] >= need && f[2] >= need && f[3] >= need)
            break;
    }
}

__device__ inline void load_h16(const uint32* pF, const uint32* pB, s8v* aF) {
    asm volatile(
        "global_load_dwordx4 %0, %16, off sc1\n\t"
        "global_load_dwordx4 %1, %16, off offset:64 sc1\n\t"
        "global_load_dwordx4 %2, %16, off offset:128 sc1\n\t"
        "global_load_dwordx4 %3, %16, off offset:192 sc1\n\t"
        "global_load_dwordx4 %4, %16, off offset:256 sc1\n\t"
        "global_load_dwordx4 %5, %16, off offset:320 sc1\n\t"
        "global_load_dwordx4 %6, %16, off offset:384 sc1\n\t"
        "global_load_dwordx4 %7, %16, off offset:448 sc1\n\t"
        "global_load_dwordx4 %8, %17, off sc1\n\t"
        "global_load_dwordx4 %9, %17, off offset:64 sc1\n\t"
        "global_load_dwordx4 %10, %17, off offset:128 sc1\n\t"
        "global_load_dwordx4 %11, %17, off offset:192 sc1\n\t"
        "global_load_dwordx4 %12, %17, off offset:256 sc1\n\t"
        "global_load_dwordx4 %13, %17, off offset:320 sc1\n\t"
        "global_load_dwordx4 %14, %17, off offset:384 sc1\n\t"
        "global_load_dwordx4 %15, %17, off offset:448 sc1\n\t"
        "s_waitcnt vmcnt(0)"
        : "=v"(aF[0]), "=v"(aF[1]), "=v"(aF[2]), "=v"(aF[3]),
          "=v"(aF[4]), "=v"(aF[5]), "=v"(aF[6]), "=v"(aF[7]),
          "=v"(aF[8]), "=v"(aF[9]), "=v"(aF[10]), "=v"(aF[11]),
          "=v"(aF[12]), "=v"(aF[13]), "=v"(aF[14]), "=v"(aF[15])
        : "v"(pF), "v"(pB)
        : "memory");
}

__global__ __launch_bounds__(256, 1) void lstm_kernel(
    const bf16* __restrict__ WhhF, const bf16* __restrict__ WhhB, // [1024][256]
    const float* __restrict__ gatesF, const float* __restrict__ gatesB, // [64][32][1024]
    uint32* __restrict__ hx,  // [2 grp][2 dir][2 slot][16][128] packed 2xbf16
    float* __restrict__ out,  // [32][64][512]
    int* __restrict__ bar)    // [2 grp][16] flags (poison-safe: negative)
{
    int bi  = blockIdx.x;
    int g   = bi >> 2;        // batch group (16 batches)
    int pid = bi & 3;         // j-slice
    int jb  = pid * 64;
    int wv = threadIdx.x >> 6, lane = threadIdx.x & 63;
    int lo = lane & 15, hi = lane >> 4;
    int j0 = jb + wv * 16;

    uint32* hxg  = hx + (size_t)g * 8192;   // dir*4096 + slot*2048 + b*128 + jw
    int*    flags = bar + g * 16;

    // Whh fragments for BOTH dirs (64 s8v = 256 VGPR)
    s8v whh[2][4][8];
#pragma unroll
    for (int q = 0; q < 4; ++q)
#pragma unroll
        for (int kt = 0; kt < 8; ++kt) {
            whh[0][q][kt] = *(const s8v*)(WhhF + (size_t)(q * 256 + j0 + lo) * 256 + kt * 32 + hi * 8);
            whh[1][q][kt] = *(const s8v*)(WhhB + (size_t)(q * 256 + j0 + lo) * 256 + kt * 32 + hi * 8);
        }

    // zero slot 0, both dirs, own jw slice (32 dwords per row)
    int jbw = jb >> 1;
    for (int x = threadIdx.x; x < 1024; x += 256) {
        int d = x >> 9, b = (x >> 5) & 15, jw = jbw + (x & 31);
        __hip_atomic_store(&hxg[d * 4096 + b * 128 + jw], 0u,
                           __ATOMIC_RELAXED, __HIP_MEMORY_SCOPE_AGENT);
    }
    __syncthreads();    // drains zero-stores (vmcnt 0 before s_barrier)
    if (threadIdx.x == 0)
        __hip_atomic_store(&flags[pid], 1, __ATOMIC_RELAXED,
                           __HIP_MEMORY_SCOPE_AGENT);

    // prologue: wait for all peers' init, load h(0) (zeros) for both dirs
    poll4(flags, 1);
    s8v aF[16];   // [0..7] fwd kt, [8..15] bwd kt
    {
        const uint32* pF = hxg + lo * 128 + hi * 4;
        load_h16(pF, pF + 4096, aF);
    }

    float cstf[4] = {0.f,0.f,0.f,0.f}, cstb[4] = {0.f,0.f,0.f,0.f};

    for (int t = 0; t < 64; ++t) {
        int tpF = t, tpB = 63 - t;
        int slot = (t + 1) & 1;

        // gate inputs both dirs (L2-warm; latency hides under MFMA)
        float gvf[4][4], gvb[4][4];
#pragma unroll
        for (int i = 0; i < 4; ++i) {
            int bg = g * 16 + hi * 4 + i;
#pragma unroll
            for (int q = 0; q < 4; ++q) {
                gvf[q][i] = gatesF[(size_t)tpF * 32768 + bg * 1024 + q * 256 + j0 + lo];
                gvb[q][i] = gatesB[(size_t)tpB * 32768 + bg * 1024 + q * 256 + j0 + lo];
            }
        }

        // ---- forward direction ----
        float hvf[4];
        {
            f4v acc[4];
#pragma unroll
            for (int q = 0; q < 4; ++q) acc[q] = (f4v){0.f,0.f,0.f,0.f};
#pragma unroll
            for (int kt = 0; kt < 8; ++kt)
#pragma unroll
                for (int q = 0; q < 4; ++q)
                    acc[q] = mfma16(aF[kt], whh[0][q][kt], acc[q]);
#pragma unroll
            for (int i = 0; i < 4; ++i) {
                float xi = acc[0][i] + gvf[0][i];
                float xf = acc[1][i] + gvf[1][i];
                float xg = acc[2][i] + gvf[2][i];
                float xo = acc[3][i] + gvf[3][i];
                float c = sigf(xf) * cstf[i] + sigf(xi) * tanh_(xg);
                cstf[i] = c;
                hvf[i] = sigf(xo) * tanh_(c);
            }
        }
        // store fwd h (latency hides under bwd compute)
        if (t < 63) {
            uint32* hw = hxg + slot * 2048;
#pragma unroll
            for (int i = 0; i < 4; ++i) {
                float o2 = __shfl_xor(hvf[i], 1);
                if (!(lane & 1)) {
                    uint32 pk = (uint32)__bfloat16_as_ushort(__float2bfloat16(hvf[i]))
                              | ((uint32)__bfloat16_as_ushort(__float2bfloat16(o2)) << 16);
                    __hip_atomic_store(&hw[(hi * 4 + i) * 128 + ((j0 + lo) >> 1)], pk,
                                       __ATOMIC_RELAXED, __HIP_MEMORY_SCOPE_AGENT);
                }
            }
        }

        // ---- backward direction ----
        float hvb[4];
        {
            f4v acc[4];
#pragma unroll
            for (int q = 0; q < 4; ++q) acc[q] = (f4v){0.f,0.f,0.f,0.f};
#pragma unroll
            for (int kt = 0; kt < 8; ++kt)
#pragma unroll
                for (int q = 0; q < 4; ++q)
                    acc[q] = mfma16(aF[8 + kt], whh[1][q][kt], acc[q]);
#pragma unroll
            for (int i = 0; i < 4; ++i) {
                float xi = acc[0][i] + gvb[0][i];
                float xf = acc[1][i] + gvb[1][i];
                float xg = acc[2][i] + gvb[2][i];
                float xo = acc[3][i] + gvb[3][i];
                float c = sigf(xf) * cstb[i] + sigf(xi) * tanh_(xg);
                cstb[i] = c;
                hvb[i] = sigf(xo) * tanh_(c);
            }
        }
        if (t < 63) {
            uint32* hw = hxg + 4096 + slot * 2048;
#pragma unroll
            for (int i = 0; i < 4; ++i) {
                float o2 = __shfl_xor(hvb[i], 1);
                if (!(lane & 1)) {
                    uint32 pk = (uint32)__bfloat16_as_ushort(__float2bfloat16(hvb[i]))
                              | ((uint32)__bfloat16_as_ushort(__float2bfloat16(o2)) << 16);
                    __hip_atomic_store(&hw[(hi * 4 + i) * 128 + ((j0 + lo) >> 1)], pk,
                                       __ATOMIC_RELAXED, __HIP_MEMORY_SCOPE_AGENT);
                }
            }
        }

        // output stores (normal cached stores)
#pragma unroll
        for (int i = 0; i < 4; ++i) {
            int bg = g * 16 + hi * 4 + i;
            out[((size_t)bg * 64 + tpF) * 512 + j0 + lo]       = hvf[i];
            out[((size_t)bg * 64 + tpB) * 512 + 256 + j0 + lo] = hvb[i];
        }

        if (t < 63) {
            __syncthreads();   // drains ALL stores (vmcnt 0) + joins waves
            if (threadIdx.x == 0)
                __hip_atomic_store(&flags[pid], t + 2, __ATOMIC_RELAXED,
                                   __HIP_MEMORY_SCOPE_AGENT);
            poll4(flags, t + 2);
            const uint32* pF = hxg + slot * 2048 + lo * 128 + hi * 4;
            load_h16(pF, pF + 4096, aF);
        }
    }
}

// ---------------------------------------------------------------------------
// action = max over T of output; action_semantics = action @ fc_W^T + fc_b
// ---------------------------------------------------------------------------
__global__ __launch_bounds__(256) void final_kernel(
    const float* __restrict__ out,   // [32][64][512]
    const float* __restrict__ fcW,   // [300][512]
    const float* __restrict__ fcb,   // [300]
    float* __restrict__ osem)        // [32][300]
{
    int b = blockIdx.x, tid = threadIdx.x;
    __shared__ float act[512];
    for (int h = tid; h < 512; h += 256) {
        float m = -1e30f;
        const float* p = out + (size_t)b * 64 * 512 + h;
#pragma unroll 8
        for (int t = 0; t < 64; ++t) m = fmaxf(m, p[t * 512]);
        act[h] = m;
    }
    __syncthreads();
    int wv = tid >> 6, lane = tid & 63;
    for (int s = wv; s < 300; s += 4) {
        const float* wrow = fcW + (size_t)s * 512 + lane * 8;
        float a = 0.f;
#pragma unroll
        for (int i = 0; i < 8; ++i) a += act[lane * 8 + i] * wrow[i];
#pragma unroll
        for (int off = 32; off; off >>= 1) a += __shfl_xor(a, off);
        if (lane == 0) osem[b * 300 + s] = a + fcb[s];
    }
}

// ---------------------------------------------------------------------------
extern "C" void kernel_launch(void* const* d_in, const int* in_sizes, int n_in,
                              void* d_out, int out_size, void* d_ws, size_t ws_size,
                              hipStream_t stream)
{
    const float* visual  = (const float*)d_in[0];
    const float* objects = (const float*)d_in[1];
    const float* lin_W   = (const float*)d_in[2];
    const float* lin_b   = (const float*)d_in[3];
    const float* W_W     = (const float*)d_in[4];
    const float* W_b     = (const float*)d_in[5];
    const float* U_W     = (const float*)d_in[6];
    const float* U_b     = (const float*)d_in[7];
    const float* b_attn  = (const float*)d_in[8];
    const float* w_W     = (const float*)d_in[9];
    const float* w_b     = (const float*)d_in[10];
    const float* Wih_f   = (const float*)d_in[11];
    const float* Whh_f   = (const float*)d_in[12];
    const float* bih_f   = (const float*)d_in[13];
    const float* bhh_f   = (const float*)d_in[14];
    const float* Wih_b   = (const float*)d_in[15];
    const float* Whh_b   = (const float*)d_in[16];
    const float* bih_b   = (const float*)d_in[17];
    const float* bhh_b   = (const float*)d_in[18];
    const float* fc_W    = (const float*)d_in[19];
    const float* fc_b    = (const float*)d_in[20];

    char* ws = (char*)d_ws;
    size_t o = 0;
    bf16*   feats   = (bf16*)(ws + o);   o += (size_t)2048 * 1024 * 2;
    float*  Wf      = (float*)(ws + o);  o += (size_t)2048 * 512 * 4;
    float*  Uo      = (float*)(ws + o);  o += (size_t)1152 * 512 * 4;
    float*  gatesF  = (float*)(ws + o);  o += (size_t)2048 * 1024 * 4;
    float*  gatesB  = (float*)(ws + o);  o += (size_t)2048 * 1024 * 4;
    uint32* hx      = (uint32*)(ws + o); o += (size_t)2 * 8192 * 4;
    int*    bar     = (int*)(ws + o);    o += 256;
    bf16*  visual_b  = (bf16*)(ws + o); o += (size_t)4194304 * 2;
    bf16*  objects_b = (bf16*)(ws + o); o += (size_t)589824 * 2;
    bf16*  lin_Wb    = (bf16*)(ws + o); o += (size_t)1048576 * 2;
    bf16*  W_Wb      = (bf16*)(ws + o); o += (size_t)262144 * 2;
    bf16*  U_Wb      = (bf16*)(ws + o); o += (size_t)262144 * 2;
    bf16*  Wih_fb    = (bf16*)(ws + o); o += (size_t)1048576 * 2;
    bf16*  Whh_fb    = (bf16*)(ws + o); o += (size_t)262144 * 2;
    bf16*  Wih_bb    = (bf16*)(ws + o); o += (size_t)1048576 * 2;
    bf16*  Whh_bb    = (bf16*)(ws + o); o += (size_t)262144 * 2;

    CvtJobs cj;
    const float* srcs[9] = {visual, objects, lin_W, W_W, U_W, Wih_f, Whh_f, Wih_b, Whh_b};
    bf16* dsts[9] = {visual_b, objects_b, lin_Wb, W_Wb, U_Wb, Wih_fb, Whh_fb, Wih_bb, Whh_bb};
    int ns[9] = {4194304, 589824, 1048576, 262144, 262144, 1048576, 262144, 1048576, 262144};
    int acc_b = 0;
    for (int i = 0; i < 9; ++i) {
        cj.src[i] = srcs[i];
        cj.dst[i] = dsts[i];
        cj.start[i] = acc_b;
        acc_b += ns[i] / 1024;
    }
    cj.start[9] = acc_b;

    dim3 blk(256);
    cvt_kernel<<<acc_b, blk, 0, stream>>>(cj);

    // f3d -> feats[:, :512]   (M=2048,N=512,K=2048), 16x4 tiles
    gemm_tile<bf16><<<64, blk, 0, stream>>>(visual_b, 2048, lin_Wb, lin_b, nullptr,
                                            feats, 1024, 2048, 4, 0);
    // Uo' = objects@U_W^T + (U_b + b_attn)   (M=1152,N=512,K=512), 9x4 tiles
    gemm_tile<float><<<36, blk, 0, stream>>>(objects_b, 512, U_Wb, U_b, b_attn,
                                             Uo, 512, 512, 4, 0);
    // Wf = f3d@W_W^T + W_b   (M=2048,N=512,K=512), 16x4 tiles
    gemm_tile<float><<<64, blk, 0, stream>>>(feats, 1024, W_Wb, W_b, nullptr,
                                             Wf, 512, 512, 4, 0);
    // fused attention -> feats[:, 512:]
    attn_kernel<<<2048, blk, 0, stream>>>(Wf, Uo, w_W, w_b, feats);
    // gate input projections -> [T][B][1024]   (M=2048,N=1024,K=1024), 16x8
    gemm_tile<float><<<128, blk, 0, stream>>>(feats, 1024, Wih_fb, bih_f, bhh_f,
                                              gatesF, 1024, 1024, 8, 1);
    gemm_tile<float><<<128, blk, 0, stream>>>(feats, 1024, Wih_bb, bih_b, bhh_b,
                                              gatesB, 1024, 1024, 8, 1);
    // recurrent BiLSTM -> d_out[0 .. 1048575]
    lstm_kernel<<<8, blk, 0, stream>>>(Whh_fb, Whh_bb, gatesF, gatesB, hx,
                                       (float*)d_out, bar);
    // action max + fc -> d_out[1048576 ..]
    final_kernel<<<32, blk, 0, stream>>>((float*)d_out, fc_W, fc_b,
                                         (float*)d_out + 1048576);
}